// Round 1
// baseline (275.905 us; speedup 1.0000x reference)
//
#include <hip/hip_runtime.h>

#define NNODES 15279
#define NEDGE  488928
#define INCH   1024
#define NHID   512
#define NCLS   16

using short8 = __attribute__((ext_vector_type(8))) short;
using f32x4  = __attribute__((ext_vector_type(4))) float;

__device__ __forceinline__ float bf2f(unsigned short u) {
  union { unsigned int i; float f; } v; v.i = ((unsigned int)u) << 16; return v.f;
}
__device__ __forceinline__ unsigned short f2bf(float f) {
  union { float ff; unsigned int i; } v; v.ff = f;
  return (unsigned short)((v.i + 0x7FFFu + ((v.i >> 16) & 1u)) >> 16);
}

// ---------- embedding lookup + relu -> bf16 h [NNODES][INCH] ----------
__global__ __launch_bounds__(256) void k_embed(const int* __restrict__ x,
                                               const float* __restrict__ emb,
                                               unsigned short* __restrict__ h) {
  int n = blockIdx.x;
  int c4 = threadIdx.x;                 // granule of 4 floats; 256 granules per row
  int s = c4 >> 5;                      // which of 8 embedding slots
  int d = (c4 & 31) * 4;                // offset within 128-dim embedding
  int idx = x[n * 8 + s];
  const float4 v = *(const float4*)&emb[idx * 128 + d];
  unsigned int lo = (unsigned int)f2bf(fmaxf(v.x, 0.f)) | ((unsigned int)f2bf(fmaxf(v.y, 0.f)) << 16);
  unsigned int hi = (unsigned int)f2bf(fmaxf(v.z, 0.f)) | ((unsigned int)f2bf(fmaxf(v.w, 0.f)) << 16);
  uint2 o; o.x = lo; o.y = hi;
  *(uint2*)&h[n * INCH + c4 * 4] = o;
}

// ---------- W1 [INCH][NHID] fp32 -> w1t [NHID][INCH] bf16 (LDS-tiled transpose) ----------
__global__ __launch_bounds__(256) void k_w1t(const float* __restrict__ W1,
                                             unsigned short* __restrict__ w1t) {
  __shared__ float tile[64][65];
  int k0 = blockIdx.x * 64, n0 = blockIdx.y * 64;
  int t = threadIdx.x;
  int c = t & 63, r4 = t >> 6;
  for (int i = 0; i < 16; ++i) {
    int r = r4 + i * 4;
    tile[r][c] = W1[(k0 + r) * NHID + n0 + c];
  }
  __syncthreads();
  for (int i = 0; i < 16; ++i) {
    int nr = r4 + i * 4;
    w1t[(size_t)(n0 + nr) * INCH + k0 + c] = f2bf(tile[c][nr]);
  }
}

// ---------- CSR build ----------
__global__ __launch_bounds__(256) void k_hist(const int* __restrict__ rows,
                                              int* __restrict__ counts) {
  int e = blockIdx.x * 256 + threadIdx.x;
  if (e < NEDGE) atomicAdd(&counts[rows[e]], 1);
}

__global__ __launch_bounds__(256) void k_scan(const int* __restrict__ counts,
                                              int* __restrict__ rs) {
  __shared__ int part[256];
  int t = threadIdx.x;
  int lo = t * 60, hi = lo + 60;
  if (hi > NNODES) hi = NNODES;
  if (lo > NNODES) lo = NNODES;
  int s = 0;
  for (int i = lo; i < hi; ++i) s += counts[i];
  part[t] = s;
  __syncthreads();
  if (t == 0) {
    int run = 0;
    for (int i = 0; i < 256; ++i) { int v = part[i]; part[i] = run; run += v; }
  }
  __syncthreads();
  int run = part[t];
  for (int i = lo; i < hi; ++i) { rs[i] = run; run += counts[i]; }
  if (t == 255) rs[NNODES] = run;
}

__global__ __launch_bounds__(256) void k_scatter(const int* __restrict__ rows,
                                                 const int* __restrict__ cols,
                                                 const float* __restrict__ vals,
                                                 const int* __restrict__ rs,
                                                 int* __restrict__ cursor,
                                                 int* __restrict__ scol,
                                                 float* __restrict__ sval) {
  int e = blockIdx.x * 256 + threadIdx.x;
  if (e < NEDGE) {
    int r = rows[e];
    int p = rs[r] + atomicAdd(&cursor[r], 1);
    scol[p] = cols[e];
    sval[p] = vals[e];
  }
}

// ---------- GEMM1: t1 = h @ W1  (bf16 MFMA, 128x128 tile, BK=64) ----------
// A = h [NNODES][INCH] bf16 row-major; Bt = w1t [NHID][INCH] bf16 (k-contiguous)
// LDS layout: 16B granules, granule(row,kg) stored at row*8 + (kg ^ (row&7))  (XOR swizzle)
__global__ __launch_bounds__(256) void k_gemm1(const unsigned short* __restrict__ A,
                                               const unsigned short* __restrict__ Bt,
                                               unsigned short* __restrict__ C) {
  __shared__ unsigned short As[128 * 64];
  __shared__ unsigned short Bs[128 * 64];
  const int t = threadIdx.x;
  const int m0 = (blockIdx.x >> 2) * 128;
  const int n0 = (blockIdx.x & 3) * 128;
  const int w = t >> 6, l = t & 63;
  const int wm = w >> 1, wn = w & 1;
  const int l4 = l >> 4, l15 = l & 15;
  const int rowA = wm * 64 + l15;
  const int colB = wn * 64 + l15;
  f32x4 acc[4][4] = {};

  for (int kt = 0; kt < 16; ++kt) {
    const int k0 = kt * 64;
    // stage 1024 granules for A and 1024 for B; 4+4 per thread
    for (int i = 0; i < 4; ++i) {
      int p = i * 256 + t;
      int row = p >> 3, kg = p & 7;
      int sw = (row * 8 + (kg ^ (row & 7))) * 8;
      int ga = m0 + row; ga = ga < NNODES ? ga : NNODES - 1;   // clamp tail rows
      *(short8*)&As[sw] = *(const short8*)&A[(size_t)ga * INCH + k0 + kg * 8];
      *(short8*)&Bs[sw] = *(const short8*)&Bt[(size_t)(n0 + row) * INCH + k0 + kg * 8];
    }
    __syncthreads();
    for (int kk = 0; kk < 2; ++kk) {
      short8 af[4], bfr[4];
      for (int m = 0; m < 4; ++m) {
        int r = rowA + m * 16;
        af[m] = *(const short8*)&As[(r * 8 + ((kk * 4 + l4) ^ (r & 7))) * 8];
      }
      for (int n = 0; n < 4; ++n) {
        int c = colB + n * 16;
        bfr[n] = *(const short8*)&Bs[(c * 8 + ((kk * 4 + l4) ^ (c & 7))) * 8];
      }
      for (int m = 0; m < 4; ++m)
        for (int n = 0; n < 4; ++n)
          acc[m][n] = __builtin_amdgcn_mfma_f32_16x16x32_bf16(af[m], bfr[n], acc[m][n], 0, 0, 0);
    }
    __syncthreads();
  }
  // epilogue: C/D layout col=lane&15, row=(lane>>4)*4+reg (m89-verified)
  const int rb = m0 + wm * 64 + l4 * 4;
  const int cb = n0 + wn * 64 + l15;
  for (int m = 0; m < 4; ++m)
    for (int j = 0; j < 4; ++j) {
      int r = rb + m * 16 + j;
      if (r < NNODES)
        for (int n = 0; n < 4; ++n)
          C[(size_t)r * NHID + cb + n * 16] = f2bf(acc[m][n][j]);
    }
}

// ---------- spmm1 + bias + relu: h1[r] = relu(sum_e val*t1[col] + b1) ----------
__global__ __launch_bounds__(256) void k_spmm1(const int* __restrict__ rs,
                                               const int* __restrict__ scol,
                                               const float* __restrict__ sval,
                                               const unsigned short* __restrict__ t1,
                                               const float* __restrict__ b1,
                                               unsigned short* __restrict__ h1) {
  int r = blockIdx.x;
  int f2 = threadIdx.x;                 // features 2*f2, 2*f2+1
  int e0 = rs[r], e1 = rs[r + 1];
  float a0 = 0.f, a1 = 0.f;
  for (int e = e0; e < e1; ++e) {
    int c = scol[e];
    float v = sval[e];
    unsigned int u = *(const unsigned int*)&t1[(size_t)c * NHID + f2 * 2];
    a0 += v * bf2f((unsigned short)(u & 0xffff));
    a1 += v * bf2f((unsigned short)(u >> 16));
  }
  a0 += b1[f2 * 2];  a1 += b1[f2 * 2 + 1];
  a0 = a0 > 0.f ? a0 : 0.f;
  a1 = a1 > 0.f ? a1 : 0.f;
  unsigned int o = (unsigned int)f2bf(a0) | ((unsigned int)f2bf(a1) << 16);
  *(unsigned int*)&h1[(size_t)r * NHID + f2 * 2] = o;
}

// ---------- GEMM2: t2 = h1 @ W2  (fp32 vector, K=512 N=16) ----------
__global__ __launch_bounds__(256) void k_gemm2(const unsigned short* __restrict__ h1,
                                               const float* __restrict__ W2,
                                               float* __restrict__ t2) {
  __shared__ unsigned short hs[32 * 520];   // 32 rows, padded stride 520 (bank spread)
  int r0 = blockIdx.x * 32;
  int t = threadIdx.x;
  for (int i = 0; i < 8; ++i) {
    int g = t + i * 256;
    int row = g >> 6, c8 = (g & 63) * 8;
    short8 v = {};
    int gr = r0 + row;
    if (gr < NNODES) v = *(const short8*)&h1[(size_t)gr * NHID + c8];
    *(short8*)&hs[row * 520 + c8] = v;
  }
  __syncthreads();
  int f = t & 15, rr = t >> 4;
  float a0 = 0.f, a1 = 0.f;
  for (int k = 0; k < NHID; ++k) {
    float wv = W2[k * NCLS + f];
    a0 += wv * bf2f(hs[rr * 520 + k]);
    a1 += wv * bf2f(hs[(rr + 16) * 520 + k]);
  }
  int g0 = r0 + rr, g1 = r0 + rr + 16;
  if (g0 < NNODES) t2[(size_t)g0 * NCLS + f] = a0;
  if (g1 < NNODES) t2[(size_t)g1 * NCLS + f] = a1;
}

// ---------- spmm2 + bias: out[r] = sum_e val*t2[col] + b2 ----------
__global__ __launch_bounds__(256) void k_spmm2(const int* __restrict__ rs,
                                               const int* __restrict__ scol,
                                               const float* __restrict__ sval,
                                               const float* __restrict__ t2,
                                               const float* __restrict__ b2,
                                               float* __restrict__ out) {
  int t = threadIdx.x;
  int f = t & 15, rl = t >> 4;
  int r = blockIdx.x * 16 + rl;
  if (r >= NNODES) return;
  int e0 = rs[r], e1 = rs[r + 1];
  float acc = b2[f];
  for (int e = e0; e < e1; ++e)
    acc += sval[e] * t2[(size_t)scol[e] * NCLS + f];
  out[(size_t)r * NCLS + f] = acc;
}

extern "C" void kernel_launch(void* const* d_in, const int* in_sizes, int n_in,
                              void* d_out, int out_size, void* d_ws, size_t ws_size,
                              hipStream_t stream) {
  (void)in_sizes; (void)n_in; (void)out_size; (void)ws_size;
  const int*   x    = (const int*)  d_in[0];
  const int*   rows = (const int*)  d_in[1];
  const int*   cols = (const int*)  d_in[2];
  const float* vals = (const float*)d_in[3];
  const float* emb  = (const float*)d_in[4];
  const float* W1   = (const float*)d_in[5];
  const float* b1   = (const float*)d_in[6];
  const float* W2   = (const float*)d_in[7];
  const float* b2   = (const float*)d_in[8];
  float* out = (float*)d_out;

  char* ws = (char*)d_ws;
  size_t off = 0;
  auto take = [&](size_t bytes) {
    char* p = ws + off;
    off = (off + bytes + 255) & ~(size_t)255;
    return p;
  };
  unsigned short* h    = (unsigned short*)take((size_t)NNODES * INCH * 2);
  unsigned short* w1t  = (unsigned short*)take((size_t)NHID * INCH * 2);
  unsigned short* t1   = (unsigned short*)take((size_t)NNODES * NHID * 2);
  unsigned short* h1   = (unsigned short*)take((size_t)NNODES * NHID * 2);
  float*          t2   = (float*)take((size_t)NNODES * NCLS * 4);
  int*            counts = (int*)take((size_t)NNODES * 4);
  int*            cursor = (int*)take((size_t)NNODES * 4);
  int*            rs     = (int*)take((size_t)(NNODES + 1) * 4);
  int*            scol   = (int*)take((size_t)NEDGE * 4);
  float*          sval   = (float*)take((size_t)NEDGE * 4);

  hipMemsetAsync(counts, 0, (size_t)NNODES * 4, stream);
  hipMemsetAsync(cursor, 0, (size_t)NNODES * 4, stream);

  k_embed<<<NNODES, 256, 0, stream>>>(x, emb, h);
  k_w1t<<<dim3(INCH / 64, NHID / 64), 256, 0, stream>>>(W1, w1t);
  k_hist<<<(NEDGE + 255) / 256, 256, 0, stream>>>(rows, counts);
  k_scan<<<1, 256, 0, stream>>>(counts, rs);
  k_scatter<<<(NEDGE + 255) / 256, 256, 0, stream>>>(rows, cols, vals, rs, cursor, scol, sval);
  k_gemm1<<<((NNODES + 127) / 128) * (NHID / 128), 256, 0, stream>>>(h, w1t, t1);
  k_spmm1<<<NNODES, 256, 0, stream>>>(rs, scol, sval, t1, b1, h1);
  k_gemm2<<<(NNODES + 31) / 32, 256, 0, stream>>>(h1, W2, t2);
  k_spmm2<<<(NNODES + 15) / 16, 256, 0, stream>>>(rs, scol, sval, t2, b2, out);
}

// Round 2
// 221.138 us; speedup vs baseline: 1.2477x; 1.2477x over previous
//
#include <hip/hip_runtime.h>

#define NNODES 15279
#define NEDGE  488928
#define INCH   1024
#define NHID   512
#define NCLS   16

using short8 = __attribute__((ext_vector_type(8))) short;
using f32x4  = __attribute__((ext_vector_type(4))) float;

__device__ __forceinline__ float bf2f(unsigned short u) {
  union { unsigned int i; float f; } v; v.i = ((unsigned int)u) << 16; return v.f;
}
__device__ __forceinline__ unsigned short f2bf(float f) {
  union { float ff; unsigned int i; } v; v.ff = f;
  return (unsigned short)((v.i + 0x7FFFu + ((v.i >> 16) & 1u)) >> 16);
}

// ---------- embedding lookup + relu -> bf16 h [NNODES][INCH] ----------
__global__ __launch_bounds__(256) void k_embed(const int* __restrict__ x,
                                               const float* __restrict__ emb,
                                               unsigned short* __restrict__ h) {
  int n = blockIdx.x;
  int c4 = threadIdx.x;
  int s = c4 >> 5;
  int d = (c4 & 31) * 4;
  int idx = x[n * 8 + s];
  const float4 v = *(const float4*)&emb[idx * 128 + d];
  unsigned int lo = (unsigned int)f2bf(fmaxf(v.x, 0.f)) | ((unsigned int)f2bf(fmaxf(v.y, 0.f)) << 16);
  unsigned int hi = (unsigned int)f2bf(fmaxf(v.z, 0.f)) | ((unsigned int)f2bf(fmaxf(v.w, 0.f)) << 16);
  uint2 o; o.x = lo; o.y = hi;
  *(uint2*)&h[n * INCH + c4 * 4] = o;
}

// ---------- W1 [INCH][NHID] fp32 -> w1t [NHID][INCH] bf16 ----------
__global__ __launch_bounds__(256) void k_w1t(const float* __restrict__ W1,
                                             unsigned short* __restrict__ w1t) {
  __shared__ float tile[64][65];
  int k0 = blockIdx.x * 64, n0 = blockIdx.y * 64;
  int t = threadIdx.x;
  int c = t & 63, r4 = t >> 6;
  for (int i = 0; i < 16; ++i) {
    int r = r4 + i * 4;
    tile[r][c] = W1[(k0 + r) * NHID + n0 + c];
  }
  __syncthreads();
  for (int i = 0; i < 16; ++i) {
    int nr = r4 + i * 4;
    w1t[(size_t)(n0 + nr) * INCH + k0 + c] = f2bf(tile[c][nr]);
  }
}

// ---------- CSR build ----------
__global__ __launch_bounds__(256) void k_hist(const int* __restrict__ rows,
                                              int* __restrict__ counts) {
  int e = blockIdx.x * 256 + threadIdx.x;
  if (e < NEDGE) atomicAdd(&counts[rows[e]], 1);
}

__global__ __launch_bounds__(256) void k_scan(const int* __restrict__ counts,
                                              int* __restrict__ rs) {
  int t = threadIdx.x;
  int lo = t * 60, hi = lo + 60;
  if (hi > NNODES) hi = NNODES;
  if (lo > NNODES) lo = NNODES;
  int s = 0;
  for (int i = lo; i < hi; ++i) s += counts[i];
  // exclusive scan of s across 256 threads (4 waves)
  int lane = t & 63, wid = t >> 6;
  int v = s;
  for (int d = 1; d < 64; d <<= 1) {
    int u = __shfl_up(v, d);
    if (lane >= d) v += u;
  }
  __shared__ int wsum[4];
  if (lane == 63) wsum[wid] = v;
  __syncthreads();
  int wbase = 0;
  for (int w2 = 0; w2 < wid; ++w2) wbase += wsum[w2];
  int run = wbase + v - s;   // exclusive prefix for this thread's chunk
  for (int i = lo; i < hi; ++i) { rs[i] = run; run += counts[i]; }
  if (t == 255) rs[NNODES] = run;
}

__global__ __launch_bounds__(256) void k_scatter(const int* __restrict__ rows,
                                                 const int* __restrict__ cols,
                                                 const float* __restrict__ vals,
                                                 const int* __restrict__ rs,
                                                 int* __restrict__ cursor,
                                                 int* __restrict__ scol,
                                                 float* __restrict__ sval) {
  int e = blockIdx.x * 256 + threadIdx.x;
  if (e < NEDGE) {
    int r = rows[e];
    int p = rs[r] + atomicAdd(&cursor[r], 1);
    scol[p] = cols[e];
    sval[p] = vals[e];
  }
}

// ---------- GEMM1: t1 = h @ W1  (bf16 MFMA, 128x128 tile, BK=64, global_load_lds) ----------
// LDS linear; XOR swizzle applied on the GLOBAL source granule index (m173 pattern):
// LDS slot (row, s) holds global granule s ^ (row&7); reads use slot (kwant ^ (row&7)).
__global__ __launch_bounds__(256) void k_gemm1(const unsigned short* __restrict__ A,
                                               const unsigned short* __restrict__ Bt,
                                               unsigned short* __restrict__ C) {
  __shared__ unsigned short As[128 * 64];
  __shared__ unsigned short Bs[128 * 64];
  const int t = threadIdx.x;
  const int m0 = (blockIdx.x >> 2) * 128;
  const int n0 = (blockIdx.x & 3) * 128;
  const int w = t >> 6, l = t & 63;
  const int wm = w >> 1, wn = w & 1;
  const int l4 = l >> 4, l15 = l & 15;
  const int rowA = wm * 64 + l15;
  const int colB = wn * 64 + l15;
  f32x4 acc[4][4] = {};

  for (int kt = 0; kt < 16; ++kt) {
    const int k0 = kt * 64;
#pragma unroll
    for (int i = 0; i < 4; ++i) {
      int p = i * 256 + t;
      int row = p >> 3, kg = p & 7;
      int skg = (kg ^ (row & 7)) * 8;          // pre-swizzled source granule
      int ga = m0 + row; ga = ga < NNODES ? ga : NNODES - 1;
      __builtin_amdgcn_global_load_lds(
          (const __attribute__((address_space(1))) void*)&A[(size_t)ga * INCH + k0 + skg],
          (__attribute__((address_space(3))) void*)&As[p * 8], 16, 0, 0);
      __builtin_amdgcn_global_load_lds(
          (const __attribute__((address_space(1))) void*)&Bt[(size_t)(n0 + row) * INCH + k0 + skg],
          (__attribute__((address_space(3))) void*)&Bs[p * 8], 16, 0, 0);
    }
    __syncthreads();
    for (int kk = 0; kk < 2; ++kk) {
      short8 af[4], bfr[4];
      for (int m = 0; m < 4; ++m) {
        int r = rowA + m * 16;
        af[m] = *(const short8*)&As[(r * 8 + ((kk * 4 + l4) ^ (r & 7))) * 8];
      }
      for (int n = 0; n < 4; ++n) {
        int c = colB + n * 16;
        bfr[n] = *(const short8*)&Bs[(c * 8 + ((kk * 4 + l4) ^ (c & 7))) * 8];
      }
      for (int m = 0; m < 4; ++m)
        for (int n = 0; n < 4; ++n)
          acc[m][n] = __builtin_amdgcn_mfma_f32_16x16x32_bf16(af[m], bfr[n], acc[m][n], 0, 0, 0);
    }
    __syncthreads();
  }
  const int rb = m0 + wm * 64 + l4 * 4;
  const int cb = n0 + wn * 64 + l15;
  for (int m = 0; m < 4; ++m)
    for (int j = 0; j < 4; ++j) {
      int r = rb + m * 16 + j;
      if (r < NNODES)
        for (int n = 0; n < 4; ++n)
          C[(size_t)r * NHID + cb + n * 16] = f2bf(acc[m][n][j]);
    }
}

// ---------- spmm1 + bias + relu ----------
// 256 threads = 4 edge-lanes x 64 feature-threads (8 bf16 feats = 16B load each).
// Edge loop unrolled x2 -> 8 independent 16B gathers in flight per block.
__global__ __launch_bounds__(256) void k_spmm1(const int* __restrict__ rs,
                                               const int* __restrict__ scol,
                                               const float* __restrict__ sval,
                                               const unsigned short* __restrict__ t1,
                                               const float* __restrict__ b1,
                                               unsigned short* __restrict__ h1) {
  __shared__ float red[4 * 512];
  int r = blockIdx.x;
  int t = threadIdx.x;
  int eg = t >> 6;              // edge lane 0..3
  int f8 = (t & 63) * 8;        // feature base
  int e0 = rs[r], e1 = rs[r + 1];
  float acc[8] = {};
  int e = e0 + eg;
  for (; e + 4 < e1; e += 8) {
    int cA = scol[e], cB = scol[e + 4];
    float vA = sval[e], vB = sval[e + 4];
    short8 a = *(const short8*)&t1[(size_t)cA * NHID + f8];
    short8 b = *(const short8*)&t1[(size_t)cB * NHID + f8];
#pragma unroll
    for (int j = 0; j < 8; ++j) acc[j] += vA * bf2f((unsigned short)a[j]);
#pragma unroll
    for (int j = 0; j < 8; ++j) acc[j] += vB * bf2f((unsigned short)b[j]);
  }
  if (e < e1) {
    int c = scol[e]; float v = sval[e];
    short8 a = *(const short8*)&t1[(size_t)c * NHID + f8];
#pragma unroll
    for (int j = 0; j < 8; ++j) acc[j] += v * bf2f((unsigned short)a[j]);
  }
#pragma unroll
  for (int j = 0; j < 8; ++j) red[eg * 512 + f8 + j] = acc[j];
  __syncthreads();
  int f2 = t * 2;
  float s0 = red[f2]     + red[512 + f2]     + red[1024 + f2]     + red[1536 + f2];
  float s1 = red[f2 + 1] + red[512 + f2 + 1] + red[1024 + f2 + 1] + red[1536 + f2 + 1];
  s0 = fmaxf(s0 + b1[f2], 0.f);
  s1 = fmaxf(s1 + b1[f2 + 1], 0.f);
  *(unsigned int*)&h1[(size_t)r * NHID + f2] =
      (unsigned int)f2bf(s0) | ((unsigned int)f2bf(s1) << 16);
}

// ---------- GEMM2: t2 = h1 @ W2 ----------
__global__ __launch_bounds__(256) void k_gemm2(const unsigned short* __restrict__ h1,
                                               const float* __restrict__ W2,
                                               float* __restrict__ t2) {
  __shared__ unsigned short hs[32 * 520];
  int r0 = blockIdx.x * 32;
  int t = threadIdx.x;
  for (int i = 0; i < 8; ++i) {
    int g = t + i * 256;
    int row = g >> 6, c8 = (g & 63) * 8;
    short8 v = {};
    int gr = r0 + row;
    if (gr < NNODES) v = *(const short8*)&h1[(size_t)gr * NHID + c8];
    *(short8*)&hs[row * 520 + c8] = v;
  }
  __syncthreads();
  int f = t & 15, rr = t >> 4;
  float a0 = 0.f, a1 = 0.f;
  for (int k = 0; k < NHID; ++k) {
    float wv = W2[k * NCLS + f];
    a0 += wv * bf2f(hs[rr * 520 + k]);
    a1 += wv * bf2f(hs[(rr + 16) * 520 + k]);
  }
  int g0 = r0 + rr, g1 = r0 + rr + 16;
  if (g0 < NNODES) t2[(size_t)g0 * NCLS + f] = a0;
  if (g1 < NNODES) t2[(size_t)g1 * NCLS + f] = a1;
}

// ---------- spmm2 + bias ----------
__global__ __launch_bounds__(256) void k_spmm2(const int* __restrict__ rs,
                                               const int* __restrict__ scol,
                                               const float* __restrict__ sval,
                                               const float* __restrict__ t2,
                                               const float* __restrict__ b2,
                                               float* __restrict__ out) {
  int t = threadIdx.x;
  int f = t & 15, rl = t >> 4;
  int r = blockIdx.x * 16 + rl;
  if (r >= NNODES) return;
  int e0 = rs[r], e1 = rs[r + 1];
  float a0 = 0.f, a1 = 0.f;
  int e = e0;
  for (; e + 1 < e1; e += 2) {
    a0 += sval[e]     * t2[(size_t)scol[e] * NCLS + f];
    a1 += sval[e + 1] * t2[(size_t)scol[e + 1] * NCLS + f];
  }
  if (e < e1) a0 += sval[e] * t2[(size_t)scol[e] * NCLS + f];
  out[(size_t)r * NCLS + f] = a0 + a1 + b2[f];
}

extern "C" void kernel_launch(void* const* d_in, const int* in_sizes, int n_in,
                              void* d_out, int out_size, void* d_ws, size_t ws_size,
                              hipStream_t stream) {
  (void)in_sizes; (void)n_in; (void)out_size; (void)ws_size;
  const int*   x    = (const int*)  d_in[0];
  const int*   rows = (const int*)  d_in[1];
  const int*   cols = (const int*)  d_in[2];
  const float* vals = (const float*)d_in[3];
  const float* emb  = (const float*)d_in[4];
  const float* W1   = (const float*)d_in[5];
  const float* b1   = (const float*)d_in[6];
  const float* W2   = (const float*)d_in[7];
  const float* b2   = (const float*)d_in[8];
  float* out = (float*)d_out;

  char* ws = (char*)d_ws;
  size_t off = 0;
  auto take = [&](size_t bytes) {
    char* p = ws + off;
    off = (off + bytes + 255) & ~(size_t)255;
    return p;
  };
  unsigned short* h    = (unsigned short*)take((size_t)NNODES * INCH * 2);
  unsigned short* w1t  = (unsigned short*)take((size_t)NHID * INCH * 2);
  unsigned short* t1   = (unsigned short*)take((size_t)NNODES * NHID * 2);
  unsigned short* h1   = (unsigned short*)take((size_t)NNODES * NHID * 2);
  float*          t2   = (float*)take((size_t)NNODES * NCLS * 4);
  int*            counts = (int*)take((size_t)NNODES * 4);
  int*            cursor = (int*)take((size_t)NNODES * 4);
  int*            rs     = (int*)take((size_t)(NNODES + 1) * 4);
  int*            scol   = (int*)take((size_t)NEDGE * 4);
  float*          sval   = (float*)take((size_t)NEDGE * 4);

  hipMemsetAsync(counts, 0, (size_t)NNODES * 4, stream);
  hipMemsetAsync(cursor, 0, (size_t)NNODES * 4, stream);

  k_embed<<<NNODES, 256, 0, stream>>>(x, emb, h);
  k_w1t<<<dim3(INCH / 64, NHID / 64), 256, 0, stream>>>(W1, w1t);
  k_hist<<<(NEDGE + 255) / 256, 256, 0, stream>>>(rows, counts);
  k_scan<<<1, 256, 0, stream>>>(counts, rs);
  k_scatter<<<(NEDGE + 255) / 256, 256, 0, stream>>>(rows, cols, vals, rs, cursor, scol, sval);
  k_gemm1<<<((NNODES + 127) / 128) * (NHID / 128), 256, 0, stream>>>(h, w1t, t1);
  k_spmm1<<<NNODES, 256, 0, stream>>>(rs, scol, sval, t1, b1, h1);
  k_gemm2<<<(NNODES + 31) / 32, 256, 0, stream>>>(h1, W2, t2);
  k_spmm2<<<(NNODES + 15) / 16, 256, 0, stream>>>(rs, scol, sval, t2, b2, out);
}

// Round 3
// 216.480 us; speedup vs baseline: 1.2745x; 1.0215x over previous
//
#include <hip/hip_runtime.h>

#define NNODES 15279
#define NEDGE  488928
#define INCH   1024
#define NHID   512
#define NCLS   16

using short8 = __attribute__((ext_vector_type(8))) short;
using f32x4  = __attribute__((ext_vector_type(4))) float;
using f32x2  = __attribute__((ext_vector_type(2))) float;

__device__ __forceinline__ float bf2f(unsigned short u) {
  union { unsigned int i; float f; } v; v.i = ((unsigned int)u) << 16; return v.f;
}
__device__ __forceinline__ float asf(unsigned int u) {
  union { unsigned int i; float f; } v; v.i = u; return v.f;
}
__device__ __forceinline__ unsigned short f2bf(float f) {
  union { float ff; unsigned int i; } v; v.ff = f;
  return (unsigned short)((v.i + 0x7FFFu + ((v.i >> 16) & 1u)) >> 16);
}

// ---------- embedding lookup + relu -> bf16 h [NNODES][INCH] ----------
__global__ __launch_bounds__(256) void k_embed(const int* __restrict__ x,
                                               const float* __restrict__ emb,
                                               unsigned short* __restrict__ h) {
  int n = blockIdx.x;
  int c4 = threadIdx.x;
  int s = c4 >> 5;
  int d = (c4 & 31) * 4;
  int idx = x[n * 8 + s];
  const float4 v = *(const float4*)&emb[idx * 128 + d];
  unsigned int lo = (unsigned int)f2bf(fmaxf(v.x, 0.f)) | ((unsigned int)f2bf(fmaxf(v.y, 0.f)) << 16);
  unsigned int hi = (unsigned int)f2bf(fmaxf(v.z, 0.f)) | ((unsigned int)f2bf(fmaxf(v.w, 0.f)) << 16);
  uint2 o; o.x = lo; o.y = hi;
  *(uint2*)&h[n * INCH + c4 * 4] = o;
}

// ---------- W1 [INCH][NHID] fp32 -> w1t [NHID][INCH] bf16 ----------
__global__ __launch_bounds__(256) void k_w1t(const float* __restrict__ W1,
                                             unsigned short* __restrict__ w1t) {
  __shared__ float tile[64][65];
  int k0 = blockIdx.x * 64, n0 = blockIdx.y * 64;
  int t = threadIdx.x;
  int c = t & 63, r4 = t >> 6;
  for (int i = 0; i < 16; ++i) {
    int r = r4 + i * 4;
    tile[r][c] = W1[(k0 + r) * NHID + n0 + c];
  }
  __syncthreads();
  for (int i = 0; i < 16; ++i) {
    int nr = r4 + i * 4;
    w1t[(size_t)(n0 + nr) * INCH + k0 + c] = f2bf(tile[c][nr]);
  }
}

// ---------- CSR build ----------
__global__ __launch_bounds__(256) void k_hist(const int* __restrict__ rows,
                                              int* __restrict__ counts) {
  int e = blockIdx.x * 256 + threadIdx.x;
  if (e < NEDGE) atomicAdd(&counts[rows[e]], 1);
}

__global__ __launch_bounds__(256) void k_scan(const int* __restrict__ counts,
                                              int* __restrict__ rs) {
  int t = threadIdx.x;
  int lo = t * 60, hi = lo + 60;
  if (hi > NNODES) hi = NNODES;
  if (lo > NNODES) lo = NNODES;
  int s = 0;
  for (int i = lo; i < hi; ++i) s += counts[i];
  int lane = t & 63, wid = t >> 6;
  int v = s;
  for (int d = 1; d < 64; d <<= 1) {
    int u = __shfl_up(v, d);
    if (lane >= d) v += u;
  }
  __shared__ int wsum[4];
  if (lane == 63) wsum[wid] = v;
  __syncthreads();
  int wbase = 0;
  for (int w2 = 0; w2 < wid; ++w2) wbase += wsum[w2];
  int run = wbase + v - s;
  for (int i = lo; i < hi; ++i) { rs[i] = run; run += counts[i]; }
  if (t == 255) rs[NNODES] = run;
}

__global__ __launch_bounds__(256) void k_scatter(const int* __restrict__ rows,
                                                 const int* __restrict__ cols,
                                                 const float* __restrict__ vals,
                                                 const int* __restrict__ rs,
                                                 int* __restrict__ cursor,
                                                 int* __restrict__ scol,
                                                 float* __restrict__ sval) {
  int e = blockIdx.x * 256 + threadIdx.x;
  if (e < NEDGE) {
    int r = rows[e];
    int p = rs[r] + atomicAdd(&cursor[r], 1);
    scol[p] = cols[e];
    sval[p] = vals[e];
  }
}

// ---------- GEMM1: t1s = h @ W1, written SLICE-MAJOR t1s[8][NNODES][64] ----------
__global__ __launch_bounds__(256) void k_gemm1(const unsigned short* __restrict__ A,
                                               const unsigned short* __restrict__ Bt,
                                               unsigned short* __restrict__ Cs) {
  __shared__ unsigned short As[128 * 64];
  __shared__ unsigned short Bs[128 * 64];
  const int t = threadIdx.x;
  const int m0 = (blockIdx.x >> 2) * 128;
  const int n0 = (blockIdx.x & 3) * 128;
  const int w = t >> 6, l = t & 63;
  const int wm = w >> 1, wn = w & 1;
  const int l4 = l >> 4, l15 = l & 15;
  const int rowA = wm * 64 + l15;
  const int colB = wn * 64 + l15;
  f32x4 acc[4][4] = {};

  for (int kt = 0; kt < 16; ++kt) {
    const int k0 = kt * 64;
#pragma unroll
    for (int i = 0; i < 4; ++i) {
      int p = i * 256 + t;
      int row = p >> 3, kg = p & 7;
      int skg = (kg ^ (row & 7)) * 8;
      int ga = m0 + row; ga = ga < NNODES ? ga : NNODES - 1;
      __builtin_amdgcn_global_load_lds(
          (const __attribute__((address_space(1))) void*)&A[(size_t)ga * INCH + k0 + skg],
          (__attribute__((address_space(3))) void*)&As[p * 8], 16, 0, 0);
      __builtin_amdgcn_global_load_lds(
          (const __attribute__((address_space(1))) void*)&Bt[(size_t)(n0 + row) * INCH + k0 + skg],
          (__attribute__((address_space(3))) void*)&Bs[p * 8], 16, 0, 0);
    }
    __syncthreads();
    for (int kk = 0; kk < 2; ++kk) {
      short8 af[4], bfr[4];
      for (int m = 0; m < 4; ++m) {
        int r = rowA + m * 16;
        af[m] = *(const short8*)&As[(r * 8 + ((kk * 4 + l4) ^ (r & 7))) * 8];
      }
      for (int n = 0; n < 4; ++n) {
        int c = colB + n * 16;
        bfr[n] = *(const short8*)&Bs[(c * 8 + ((kk * 4 + l4) ^ (c & 7))) * 8];
      }
      for (int m = 0; m < 4; ++m)
        for (int n = 0; n < 4; ++n)
          acc[m][n] = __builtin_amdgcn_mfma_f32_16x16x32_bf16(af[m], bfr[n], acc[m][n], 0, 0, 0);
    }
    __syncthreads();
  }
  const int rb = m0 + wm * 64 + l4 * 4;
  const int cb = n0 + wn * 64 + l15;
  for (int m = 0; m < 4; ++m)
    for (int j = 0; j < 4; ++j) {
      int r = rb + m * 16 + j;
      if (r < NNODES)
        for (int n = 0; n < 4; ++n) {
          int c = cb + n * 16;
          Cs[((size_t)(c >> 6) * NNODES + r) * 64 + (c & 63)] = f2bf(acc[m][n][j]);
        }
    }
}

// ---------- spmm1 + bias + relu, feature-sliced ----------
// blockIdx&7 = slice (matches round-robin XCD dispatch -> slice stays in one L2).
// Warp = 8 edge-lanes x 8 feat-threads; 8 rows per warp; pk_fma-friendly float2 acc.
__global__ __launch_bounds__(256) void k_spmm1(const int* __restrict__ rs,
                                               const int* __restrict__ scol,
                                               const float* __restrict__ sval,
                                               const unsigned short* __restrict__ t1s,
                                               const float* __restrict__ b1,
                                               unsigned short* __restrict__ h1) {
  int b = blockIdx.x;
  int slice = b & 7;
  int rblk = b >> 3;
  int t = threadIdx.x;
  int wid = t >> 6, lane = t & 63;
  int el = lane >> 3, ft = lane & 7;
  const unsigned short* tbase = t1s + (size_t)slice * NNODES * 64 + ft * 8;
  int fglob = slice * 64 + ft * 8;
#pragma unroll 1
  for (int i = 0; i < 8; ++i) {
    int r = rblk * 32 + wid * 8 + i;
    if (r >= NNODES) break;
    int e0 = rs[r], e1 = rs[r + 1];
    f32x2 acc[4] = {};
    for (int e = e0 + el; e < e1; e += 8) {
      int c = scol[e];
      float v = sval[e];
      uint4 a = *(const uint4*)&tbase[(size_t)c * 64];
      f32x2 v2 = {v, v};
      unsigned int ua[4] = {a.x, a.y, a.z, a.w};
#pragma unroll
      for (int d = 0; d < 4; ++d) {
        f32x2 p = {asf(ua[d] << 16), asf(ua[d] & 0xffff0000u)};
        acc[d] += v2 * p;
      }
    }
#pragma unroll
    for (int m = 8; m < 64; m <<= 1)
#pragma unroll
      for (int d = 0; d < 4; ++d) {
        acc[d].x += __shfl_xor(acc[d].x, m);
        acc[d].y += __shfl_xor(acc[d].y, m);
      }
    if (el == 0) {
      unsigned int o[4];
#pragma unroll
      for (int d = 0; d < 4; ++d) {
        float s0 = fmaxf(acc[d].x + b1[fglob + 2 * d], 0.f);
        float s1 = fmaxf(acc[d].y + b1[fglob + 2 * d + 1], 0.f);
        o[d] = (unsigned int)f2bf(s0) | ((unsigned int)f2bf(s1) << 16);
      }
      uint4 ov; ov.x = o[0]; ov.y = o[1]; ov.z = o[2]; ov.w = o[3];
      *(uint4*)&h1[(size_t)r * NHID + fglob] = ov;
    }
  }
}

// ---------- GEMM2: t2 = h1 @ W2  (MFMA 16x16x32) ----------
__global__ __launch_bounds__(256) void k_gemm2(const unsigned short* __restrict__ h1,
                                               const float* __restrict__ W2,
                                               float* __restrict__ t2) {
  __shared__ unsigned short w2t[16 * 520];   // [f][k], padded stride
  int t = threadIdx.x;
#pragma unroll
  for (int i = 0; i < 32; ++i) {
    int p = i * 256 + t;          // p = k*16 + f
    int k = p >> 4, f = p & 15;
    w2t[f * 520 + k] = f2bf(W2[p]);
  }
  __syncthreads();
  int w = t >> 6, l = t & 63;
  int l15 = l & 15, l4 = l >> 4;
  int r0 = blockIdx.x * 64 + w * 16;
  int row = r0 + l15; row = row < NNODES ? row : NNODES - 1;
  f32x4 acc = {};
#pragma unroll
  for (int kk = 0; kk < 16; ++kk) {
    short8 af = *(const short8*)&h1[(size_t)row * NHID + kk * 32 + l4 * 8];
    short8 bfr = *(const short8*)&w2t[l15 * 520 + kk * 32 + l4 * 8];
    acc = __builtin_amdgcn_mfma_f32_16x16x32_bf16(af, bfr, acc, 0, 0, 0);
  }
#pragma unroll
  for (int j = 0; j < 4; ++j) {
    int r = r0 + l4 * 4 + j;
    if (r < NNODES) t2[(size_t)r * NCLS + l15] = acc[j];
  }
}

// ---------- spmm2 + bias ----------
__global__ __launch_bounds__(256) void k_spmm2(const int* __restrict__ rs,
                                               const int* __restrict__ scol,
                                               const float* __restrict__ sval,
                                               const float* __restrict__ t2,
                                               const float* __restrict__ b2,
                                               float* __restrict__ out) {
  int t = threadIdx.x;
  int f = t & 15, rl = t >> 4;
  int r = blockIdx.x * 16 + rl;
  if (r >= NNODES) return;
  int e0 = rs[r], e1 = rs[r + 1];
  float a0 = 0.f, a1 = 0.f;
  int e = e0;
  for (; e + 1 < e1; e += 2) {
    a0 += sval[e]     * t2[(size_t)scol[e] * NCLS + f];
    a1 += sval[e + 1] * t2[(size_t)scol[e + 1] * NCLS + f];
  }
  if (e < e1) a0 += sval[e] * t2[(size_t)scol[e] * NCLS + f];
  out[(size_t)r * NCLS + f] = a0 + a1 + b2[f];
}

extern "C" void kernel_launch(void* const* d_in, const int* in_sizes, int n_in,
                              void* d_out, int out_size, void* d_ws, size_t ws_size,
                              hipStream_t stream) {
  (void)in_sizes; (void)n_in; (void)out_size; (void)ws_size;
  const int*   x    = (const int*)  d_in[0];
  const int*   rows = (const int*)  d_in[1];
  const int*   cols = (const int*)  d_in[2];
  const float* vals = (const float*)d_in[3];
  const float* emb  = (const float*)d_in[4];
  const float* W1   = (const float*)d_in[5];
  const float* b1   = (const float*)d_in[6];
  const float* W2   = (const float*)d_in[7];
  const float* b2   = (const float*)d_in[8];
  float* out = (float*)d_out;

  char* ws = (char*)d_ws;
  size_t off = 0;
  auto take = [&](size_t bytes) {
    char* p = ws + off;
    off = (off + bytes + 255) & ~(size_t)255;
    return p;
  };
  unsigned short* h    = (unsigned short*)take((size_t)NNODES * INCH * 2);
  unsigned short* w1t  = (unsigned short*)take((size_t)NHID * INCH * 2);
  unsigned short* t1s  = (unsigned short*)take((size_t)NNODES * NHID * 2);
  unsigned short* h1   = (unsigned short*)take((size_t)NNODES * NHID * 2);
  float*          t2   = (float*)take((size_t)NNODES * NCLS * 4);
  int*            counts = (int*)take((size_t)NNODES * 4);
  int*            cursor = (int*)take((size_t)NNODES * 4);
  int*            rs     = (int*)take((size_t)(NNODES + 1) * 4);
  int*            scol   = (int*)take((size_t)NEDGE * 4);
  float*          sval   = (float*)take((size_t)NEDGE * 4);

  hipMemsetAsync(counts, 0, (size_t)NNODES * 4, stream);
  hipMemsetAsync(cursor, 0, (size_t)NNODES * 4, stream);

  k_embed<<<NNODES, 256, 0, stream>>>(x, emb, h);
  k_w1t<<<dim3(INCH / 64, NHID / 64), 256, 0, stream>>>(W1, w1t);
  k_hist<<<(NEDGE + 255) / 256, 256, 0, stream>>>(rows, counts);
  k_scan<<<1, 256, 0, stream>>>(counts, rs);
  k_scatter<<<(NEDGE + 255) / 256, 256, 0, stream>>>(rows, cols, vals, rs, cursor, scol, sval);
  k_gemm1<<<((NNODES + 127) / 128) * (NHID / 128), 256, 0, stream>>>(h, w1t, t1s);
  k_spmm1<<<((NNODES + 31) / 32) * 8, 256, 0, stream>>>(rs, scol, sval, t1s, b1, h1);
  k_gemm2<<<(NNODES + 63) / 64, 256, 0, stream>>>(h1, W2, t2);
  k_spmm2<<<(NNODES + 15) / 16, 256, 0, stream>>>(rs, scol, sval, t2, b2, out);
}

// Round 4
// 205.563 us; speedup vs baseline: 1.3422x; 1.0531x over previous
//
#include <hip/hip_runtime.h>

#define NNODES 15279
#define NEDGE  488928
#define INCH   1024
#define NHID   512
#define NCLS   16

using short8 = __attribute__((ext_vector_type(8))) short;
using f32x4  = __attribute__((ext_vector_type(4))) float;
using f32x2  = __attribute__((ext_vector_type(2))) float;

__device__ __forceinline__ float bf2f(unsigned short u) {
  union { unsigned int i; float f; } v; v.i = ((unsigned int)u) << 16; return v.f;
}
__device__ __forceinline__ float asf(unsigned int u) {
  union { unsigned int i; float f; } v; v.i = u; return v.f;
}
__device__ __forceinline__ unsigned short f2bf(float f) {
  union { float ff; unsigned int i; } v; v.ff = f;
  return (unsigned short)((v.i + 0x7FFFu + ((v.i >> 16) & 1u)) >> 16);
}

// ---------- embedding lookup + relu -> bf16 h [NNODES][INCH] ----------
__global__ __launch_bounds__(256) void k_embed(const int* __restrict__ x,
                                               const float* __restrict__ emb,
                                               unsigned short* __restrict__ h) {
  int n = blockIdx.x;
  int c4 = threadIdx.x;
  int s = c4 >> 5;
  int d = (c4 & 31) * 4;
  int idx = x[n * 8 + s];
  const float4 v = *(const float4*)&emb[idx * 128 + d];
  unsigned int lo = (unsigned int)f2bf(fmaxf(v.x, 0.f)) | ((unsigned int)f2bf(fmaxf(v.y, 0.f)) << 16);
  unsigned int hi = (unsigned int)f2bf(fmaxf(v.z, 0.f)) | ((unsigned int)f2bf(fmaxf(v.w, 0.f)) << 16);
  uint2 o; o.x = lo; o.y = hi;
  *(uint2*)&h[n * INCH + c4 * 4] = o;
}

// ---------- W1 [INCH][NHID] fp32 -> w1t [NHID][INCH] bf16 ----------
__global__ __launch_bounds__(256) void k_w1t(const float* __restrict__ W1,
                                             unsigned short* __restrict__ w1t) {
  __shared__ float tile[64][65];
  int k0 = blockIdx.x * 64, n0 = blockIdx.y * 64;
  int t = threadIdx.x;
  int c = t & 63, r4 = t >> 6;
  for (int i = 0; i < 16; ++i) {
    int r = r4 + i * 4;
    tile[r][c] = W1[(k0 + r) * NHID + n0 + c];
  }
  __syncthreads();
  for (int i = 0; i < 16; ++i) {
    int nr = r4 + i * 4;
    w1t[(size_t)(n0 + nr) * INCH + k0 + c] = f2bf(tile[c][nr]);
  }
}

// ---------- CSR build ----------
__global__ __launch_bounds__(256) void k_hist(const int* __restrict__ rows,
                                              int* __restrict__ counts) {
  int e = blockIdx.x * 256 + threadIdx.x;
  if (e < NEDGE) atomicAdd(&counts[rows[e]], 1);
}

__global__ __launch_bounds__(256) void k_scan(const int* __restrict__ counts,
                                              int* __restrict__ rs) {
  int t = threadIdx.x;
  int lo = t * 60, hi = lo + 60;
  if (hi > NNODES) hi = NNODES;
  if (lo > NNODES) lo = NNODES;
  int s = 0;
  for (int i = lo; i < hi; ++i) s += counts[i];
  int lane = t & 63, wid = t >> 6;
  int v = s;
  for (int d = 1; d < 64; d <<= 1) {
    int u = __shfl_up(v, d);
    if (lane >= d) v += u;
  }
  __shared__ int wsum[4];
  if (lane == 63) wsum[wid] = v;
  __syncthreads();
  int wbase = 0;
  for (int w2 = 0; w2 < wid; ++w2) wbase += wsum[w2];
  int run = wbase + v - s;
  for (int i = lo; i < hi; ++i) { rs[i] = run; run += counts[i]; }
  if (t == 255) rs[NNODES] = run;
}

__global__ __launch_bounds__(256) void k_scatter(const int* __restrict__ rows,
                                                 const int* __restrict__ cols,
                                                 const float* __restrict__ vals,
                                                 const int* __restrict__ rs,
                                                 int* __restrict__ cursor,
                                                 int* __restrict__ scol,
                                                 float* __restrict__ sval) {
  int e = blockIdx.x * 256 + threadIdx.x;
  if (e < NEDGE) {
    int r = rows[e];
    int p = rs[r] + atomicAdd(&cursor[r], 1);
    scol[p] = cols[e];
    sval[p] = vals[e];
  }
}

// ---------- GEMM1: t1s = h @ W1, written SLICE-MAJOR t1s[8][NNODES][64] ----------
__global__ __launch_bounds__(256) void k_gemm1(const unsigned short* __restrict__ A,
                                               const unsigned short* __restrict__ Bt,
                                               unsigned short* __restrict__ Cs) {
  __shared__ unsigned short As[128 * 64];
  __shared__ unsigned short Bs[128 * 64];
  const int t = threadIdx.x;
  const int m0 = (blockIdx.x >> 2) * 128;
  const int n0 = (blockIdx.x & 3) * 128;
  const int w = t >> 6, l = t & 63;
  const int wm = w >> 1, wn = w & 1;
  const int l4 = l >> 4, l15 = l & 15;
  const int rowA = wm * 64 + l15;
  const int colB = wn * 64 + l15;
  f32x4 acc[4][4] = {};

  for (int kt = 0; kt < 16; ++kt) {
    const int k0 = kt * 64;
#pragma unroll
    for (int i = 0; i < 4; ++i) {
      int p = i * 256 + t;
      int row = p >> 3, kg = p & 7;
      int skg = (kg ^ (row & 7)) * 8;
      int ga = m0 + row; ga = ga < NNODES ? ga : NNODES - 1;
      __builtin_amdgcn_global_load_lds(
          (const __attribute__((address_space(1))) void*)&A[(size_t)ga * INCH + k0 + skg],
          (__attribute__((address_space(3))) void*)&As[p * 8], 16, 0, 0);
      __builtin_amdgcn_global_load_lds(
          (const __attribute__((address_space(1))) void*)&Bt[(size_t)(n0 + row) * INCH + k0 + skg],
          (__attribute__((address_space(3))) void*)&Bs[p * 8], 16, 0, 0);
    }
    __syncthreads();
    for (int kk = 0; kk < 2; ++kk) {
      short8 af[4], bfr[4];
      for (int m = 0; m < 4; ++m) {
        int r = rowA + m * 16;
        af[m] = *(const short8*)&As[(r * 8 + ((kk * 4 + l4) ^ (r & 7))) * 8];
      }
      for (int n = 0; n < 4; ++n) {
        int c = colB + n * 16;
        bfr[n] = *(const short8*)&Bs[(c * 8 + ((kk * 4 + l4) ^ (c & 7))) * 8];
      }
      for (int m = 0; m < 4; ++m)
        for (int n = 0; n < 4; ++n)
          acc[m][n] = __builtin_amdgcn_mfma_f32_16x16x32_bf16(af[m], bfr[n], acc[m][n], 0, 0, 0);
    }
    __syncthreads();
  }
  const int rb = m0 + wm * 64 + l4 * 4;
  const int cb = n0 + wn * 64 + l15;
  for (int m = 0; m < 4; ++m)
    for (int j = 0; j < 4; ++j) {
      int r = rb + m * 16 + j;
      if (r < NNODES)
        for (int n = 0; n < 4; ++n) {
          int c = cb + n * 16;
          Cs[((size_t)(c >> 6) * NNODES + r) * 64 + (c & 63)] = f2bf(acc[m][n][j]);
        }
    }
}

// ---------- spmm1 + bias + relu, feature-sliced, 1 row/warp, unroll x2 ----------
// blockIdx&7 = slice (round-robin XCD dispatch -> slice stays in one 4MB L2).
// Warp = 8 edge-lanes x 8 feat-threads; two independent gathers in flight.
__global__ __launch_bounds__(256) void k_spmm1(const int* __restrict__ rs,
                                               const int* __restrict__ scol,
                                               const float* __restrict__ sval,
                                               const unsigned short* __restrict__ t1s,
                                               const float* __restrict__ b1,
                                               unsigned short* __restrict__ h1) {
  int b = blockIdx.x;
  int slice = b & 7;
  int rgrp = b >> 3;
  int t = threadIdx.x;
  int wid = t >> 6, lane = t & 63;
  int el = lane >> 3, ft = lane & 7;
  int r = rgrp * 4 + wid;
  if (r >= NNODES) return;
  const unsigned short* tbase = t1s + (size_t)slice * NNODES * 64 + ft * 8;
  int fglob = slice * 64 + ft * 8;
  int e0 = rs[r], e1 = rs[r + 1];
  f32x2 acc[4] = {};
  int e = e0 + el;
  for (; e + 8 < e1; e += 16) {
    int cA = scol[e], cB = scol[e + 8];
    float vA = sval[e], vB = sval[e + 8];
    uint4 a = *(const uint4*)&tbase[(size_t)cA * 64];
    uint4 bq = *(const uint4*)&tbase[(size_t)cB * 64];
    f32x2 vA2 = {vA, vA}, vB2 = {vB, vB};
    unsigned int ua[4] = {a.x, a.y, a.z, a.w};
    unsigned int ub[4] = {bq.x, bq.y, bq.z, bq.w};
#pragma unroll
    for (int d = 0; d < 4; ++d) {
      f32x2 pa = {asf(ua[d] << 16), asf(ua[d] & 0xffff0000u)};
      f32x2 pb = {asf(ub[d] << 16), asf(ub[d] & 0xffff0000u)};
      acc[d] += vA2 * pa;
      acc[d] += vB2 * pb;
    }
  }
  if (e < e1) {
    int c = scol[e];
    float v = sval[e];
    uint4 a = *(const uint4*)&tbase[(size_t)c * 64];
    f32x2 v2 = {v, v};
    unsigned int ua[4] = {a.x, a.y, a.z, a.w};
#pragma unroll
    for (int d = 0; d < 4; ++d) {
      f32x2 p = {asf(ua[d] << 16), asf(ua[d] & 0xffff0000u)};
      acc[d] += v2 * p;
    }
  }
#pragma unroll
  for (int m = 8; m < 64; m <<= 1)
#pragma unroll
    for (int d = 0; d < 4; ++d) {
      acc[d].x += __shfl_xor(acc[d].x, m);
      acc[d].y += __shfl_xor(acc[d].y, m);
    }
  if (el == 0) {
    unsigned int o[4];
#pragma unroll
    for (int d = 0; d < 4; ++d) {
      float s0 = fmaxf(acc[d].x + b1[fglob + 2 * d], 0.f);
      float s1 = fmaxf(acc[d].y + b1[fglob + 2 * d + 1], 0.f);
      o[d] = (unsigned int)f2bf(s0) | ((unsigned int)f2bf(s1) << 16);
    }
    uint4 ov; ov.x = o[0]; ov.y = o[1]; ov.z = o[2]; ov.w = o[3];
    *(uint4*)&h1[(size_t)r * NHID + fglob] = ov;
  }
}

// ---------- GEMM2: t2 = h1 @ W2  (MFMA 16x16x32) ----------
__global__ __launch_bounds__(256) void k_gemm2(const unsigned short* __restrict__ h1,
                                               const float* __restrict__ W2,
                                               float* __restrict__ t2) {
  __shared__ unsigned short w2t[16 * 520];
  int t = threadIdx.x;
#pragma unroll
  for (int i = 0; i < 32; ++i) {
    int p = i * 256 + t;
    int k = p >> 4, f = p & 15;
    w2t[f * 520 + k] = f2bf(W2[p]);
  }
  __syncthreads();
  int w = t >> 6, l = t & 63;
  int l15 = l & 15, l4 = l >> 4;
  int r0 = blockIdx.x * 64 + w * 16;
  int row = r0 + l15; row = row < NNODES ? row : NNODES - 1;
  f32x4 acc = {};
#pragma unroll
  for (int kk = 0; kk < 16; ++kk) {
    short8 af = *(const short8*)&h1[(size_t)row * NHID + kk * 32 + l4 * 8];
    short8 bfr = *(const short8*)&w2t[l15 * 520 + kk * 32 + l4 * 8];
    acc = __builtin_amdgcn_mfma_f32_16x16x32_bf16(af, bfr, acc, 0, 0, 0);
  }
#pragma unroll
  for (int j = 0; j < 4; ++j) {
    int r = r0 + l4 * 4 + j;
    if (r < NNODES) t2[(size_t)r * NCLS + l15] = acc[j];
  }
}

// ---------- spmm2 + bias ----------
__global__ __launch_bounds__(256) void k_spmm2(const int* __restrict__ rs,
                                               const int* __restrict__ scol,
                                               const float* __restrict__ sval,
                                               const float* __restrict__ t2,
                                               const float* __restrict__ b2,
                                               float* __restrict__ out) {
  int t = threadIdx.x;
  int f = t & 15, rl = t >> 4;
  int r = blockIdx.x * 16 + rl;
  if (r >= NNODES) return;
  int e0 = rs[r], e1 = rs[r + 1];
  float a0 = 0.f, a1 = 0.f;
  int e = e0;
  for (; e + 1 < e1; e += 2) {
    a0 += sval[e]     * t2[(size_t)scol[e] * NCLS + f];
    a1 += sval[e + 1] * t2[(size_t)scol[e + 1] * NCLS + f];
  }
  if (e < e1) a0 += sval[e] * t2[(size_t)scol[e] * NCLS + f];
  out[(size_t)r * NCLS + f] = a0 + a1 + b2[f];
}

extern "C" void kernel_launch(void* const* d_in, const int* in_sizes, int n_in,
                              void* d_out, int out_size, void* d_ws, size_t ws_size,
                              hipStream_t stream) {
  (void)in_sizes; (void)n_in; (void)out_size; (void)ws_size;
  const int*   x    = (const int*)  d_in[0];
  const int*   rows = (const int*)  d_in[1];
  const int*   cols = (const int*)  d_in[2];
  const float* vals = (const float*)d_in[3];
  const float* emb  = (const float*)d_in[4];
  const float* W1   = (const float*)d_in[5];
  const float* b1   = (const float*)d_in[6];
  const float* W2   = (const float*)d_in[7];
  const float* b2   = (const float*)d_in[8];
  float* out = (float*)d_out;

  char* ws = (char*)d_ws;
  size_t off = 0;
  auto take = [&](size_t bytes) {
    char* p = ws + off;
    off = (off + bytes + 255) & ~(size_t)255;
    return p;
  };
  unsigned short* h    = (unsigned short*)take((size_t)NNODES * INCH * 2);
  unsigned short* w1t  = (unsigned short*)take((size_t)NHID * INCH * 2);
  unsigned short* t1s  = (unsigned short*)take((size_t)NNODES * NHID * 2);
  unsigned short* h1   = (unsigned short*)take((size_t)NNODES * NHID * 2);
  float*          t2   = (float*)take((size_t)NNODES * NCLS * 4);
  int*            counts = (int*)take((size_t)NNODES * 4);
  int*            cursor = (int*)take((size_t)NNODES * 4);
  int*            rs     = (int*)take((size_t)(NNODES + 1) * 4);
  int*            scol   = (int*)take((size_t)NEDGE * 4);
  float*          sval   = (float*)take((size_t)NEDGE * 4);

  hipMemsetAsync(counts, 0, (size_t)NNODES * 4, stream);
  hipMemsetAsync(cursor, 0, (size_t)NNODES * 4, stream);

  k_embed<<<NNODES, 256, 0, stream>>>(x, emb, h);
  k_w1t<<<dim3(INCH / 64, NHID / 64), 256, 0, stream>>>(W1, w1t);
  k_hist<<<(NEDGE + 255) / 256, 256, 0, stream>>>(rows, counts);
  k_scan<<<1, 256, 0, stream>>>(counts, rs);
  k_scatter<<<(NEDGE + 255) / 256, 256, 0, stream>>>(rows, cols, vals, rs, cursor, scol, sval);
  k_gemm1<<<((NNODES + 127) / 128) * (NHID / 128), 256, 0, stream>>>(h, w1t, t1s);
  k_spmm1<<<((NNODES + 3) / 4) * 8, 256, 0, stream>>>(rs, scol, sval, t1s, b1, h1);
  k_gemm2<<<(NNODES + 63) / 64, 256, 0, stream>>>(h1, W2, t2);
  k_spmm2<<<(NNODES + 15) / 16, 256, 0, stream>>>(rs, scol, sval, t2, b2, out);
}

// Round 5
// 184.393 us; speedup vs baseline: 1.4963x; 1.1148x over previous
//
#include <hip/hip_runtime.h>

#define NNODES 15279
#define NEDGE  488928
#define INCH   1024
#define NHID   512
#define NCLS   16

using short8 = __attribute__((ext_vector_type(8))) short;
using f32x4  = __attribute__((ext_vector_type(4))) float;
using f32x2  = __attribute__((ext_vector_type(2))) float;

__device__ __forceinline__ float bf2f(unsigned short u) {
  union { unsigned int i; float f; } v; v.i = ((unsigned int)u) << 16; return v.f;
}
__device__ __forceinline__ float asf(unsigned int u) {
  union { unsigned int i; float f; } v; v.i = u; return v.f;
}
__device__ __forceinline__ unsigned short f2bf(float f) {
  union { float ff; unsigned int i; } v; v.ff = f;
  return (unsigned short)((v.i + 0x7FFFu + ((v.i >> 16) & 1u)) >> 16);
}

// ---------- embedding lookup + relu -> bf16 h [NNODES][INCH] ----------
__global__ __launch_bounds__(256) void k_embed(const int* __restrict__ x,
                                               const float* __restrict__ emb,
                                               unsigned short* __restrict__ h) {
  int n = blockIdx.x;
  int c4 = threadIdx.x;
  int s = c4 >> 5;
  int d = (c4 & 31) * 4;
  int idx = x[n * 8 + s];
  const float4 v = *(const float4*)&emb[idx * 128 + d];
  unsigned int lo = (unsigned int)f2bf(fmaxf(v.x, 0.f)) | ((unsigned int)f2bf(fmaxf(v.y, 0.f)) << 16);
  unsigned int hi = (unsigned int)f2bf(fmaxf(v.z, 0.f)) | ((unsigned int)f2bf(fmaxf(v.w, 0.f)) << 16);
  uint2 o; o.x = lo; o.y = hi;
  *(uint2*)&h[n * INCH + c4 * 4] = o;
}

// ---------- W1 [INCH][NHID] fp32 -> w1t [NHID][INCH] bf16 ----------
__global__ __launch_bounds__(256) void k_w1t(const float* __restrict__ W1,
                                             unsigned short* __restrict__ w1t) {
  __shared__ float tile[64][65];
  int k0 = blockIdx.x * 64, n0 = blockIdx.y * 64;
  int t = threadIdx.x;
  int c = t & 63, r4 = t >> 6;
  for (int i = 0; i < 16; ++i) {
    int r = r4 + i * 4;
    tile[r][c] = W1[(k0 + r) * NHID + n0 + c];
  }
  __syncthreads();
  for (int i = 0; i < 16; ++i) {
    int nr = r4 + i * 4;
    w1t[(size_t)(n0 + nr) * INCH + k0 + c] = f2bf(tile[c][nr]);
  }
}

// ---------- CSR build ----------
__global__ __launch_bounds__(256) void k_hist(const int* __restrict__ rows,
                                              int* __restrict__ counts) {
  int e = blockIdx.x * 256 + threadIdx.x;
  if (e < NEDGE) atomicAdd(&counts[rows[e]], 1);
}

__global__ __launch_bounds__(256) void k_scan(const int* __restrict__ counts,
                                              int* __restrict__ rs) {
  int t = threadIdx.x;
  int lo = t * 60, hi = lo + 60;
  if (hi > NNODES) hi = NNODES;
  if (lo > NNODES) lo = NNODES;
  int s = 0;
  for (int i = lo; i < hi; ++i) s += counts[i];
  int lane = t & 63, wid = t >> 6;
  int v = s;
  for (int d = 1; d < 64; d <<= 1) {
    int u = __shfl_up(v, d);
    if (lane >= d) v += u;
  }
  __shared__ int wsum[4];
  if (lane == 63) wsum[wid] = v;
  __syncthreads();
  int wbase = 0;
  for (int w2 = 0; w2 < wid; ++w2) wbase += wsum[w2];
  int run = wbase + v - s;
  for (int i = lo; i < hi; ++i) { rs[i] = run; run += counts[i]; }
  if (t == 255) rs[NNODES] = run;
}

__global__ __launch_bounds__(256) void k_scatter(const int* __restrict__ rows,
                                                 const int* __restrict__ cols,
                                                 const float* __restrict__ vals,
                                                 const int* __restrict__ rs,
                                                 int* __restrict__ cursor,
                                                 int* __restrict__ scol,
                                                 int* __restrict__ scolb,
                                                 float* __restrict__ sval) {
  int e = blockIdx.x * 256 + threadIdx.x;
  if (e < NEDGE) {
    int r = rows[e];
    int p = rs[r] + atomicAdd(&cursor[r], 1);
    int c = cols[e];
    scol[p] = c;
    scolb[p] = c * 128;      // byte offset into a 64-wide bf16 slice row
    sval[p] = vals[e];
  }
}

// ---------- GEMM1: t1s = h @ W1, written SLICE-MAJOR t1s[8][NNODES][64] ----------
__global__ __launch_bounds__(256) void k_gemm1(const unsigned short* __restrict__ A,
                                               const unsigned short* __restrict__ Bt,
                                               unsigned short* __restrict__ Cs) {
  __shared__ unsigned short As[128 * 64];
  __shared__ unsigned short Bs[128 * 64];
  const int t = threadIdx.x;
  const int m0 = (blockIdx.x >> 2) * 128;
  const int n0 = (blockIdx.x & 3) * 128;
  const int w = t >> 6, l = t & 63;
  const int wm = w >> 1, wn = w & 1;
  const int l4 = l >> 4, l15 = l & 15;
  const int rowA = wm * 64 + l15;
  const int colB = wn * 64 + l15;
  f32x4 acc[4][4] = {};

  for (int kt = 0; kt < 16; ++kt) {
    const int k0 = kt * 64;
#pragma unroll
    for (int i = 0; i < 4; ++i) {
      int p = i * 256 + t;
      int row = p >> 3, kg = p & 7;
      int skg = (kg ^ (row & 7)) * 8;
      int ga = m0 + row; ga = ga < NNODES ? ga : NNODES - 1;
      __builtin_amdgcn_global_load_lds(
          (const __attribute__((address_space(1))) void*)&A[(size_t)ga * INCH + k0 + skg],
          (__attribute__((address_space(3))) void*)&As[p * 8], 16, 0, 0);
      __builtin_amdgcn_global_load_lds(
          (const __attribute__((address_space(1))) void*)&Bt[(size_t)(n0 + row) * INCH + k0 + skg],
          (__attribute__((address_space(3))) void*)&Bs[p * 8], 16, 0, 0);
    }
    __syncthreads();
    for (int kk = 0; kk < 2; ++kk) {
      short8 af[4], bfr[4];
      for (int m = 0; m < 4; ++m) {
        int r = rowA + m * 16;
        af[m] = *(const short8*)&As[(r * 8 + ((kk * 4 + l4) ^ (r & 7))) * 8];
      }
      for (int n = 0; n < 4; ++n) {
        int c = colB + n * 16;
        bfr[n] = *(const short8*)&Bs[(c * 8 + ((kk * 4 + l4) ^ (c & 7))) * 8];
      }
      for (int m = 0; m < 4; ++m)
        for (int n = 0; n < 4; ++n)
          acc[m][n] = __builtin_amdgcn_mfma_f32_16x16x32_bf16(af[m], bfr[n], acc[m][n], 0, 0, 0);
    }
    __syncthreads();
  }
  const int rb = m0 + wm * 64 + l4 * 4;
  const int cb = n0 + wn * 64 + l15;
  for (int m = 0; m < 4; ++m)
    for (int j = 0; j < 4; ++j) {
      int r = rb + m * 16 + j;
      if (r < NNODES)
        for (int n = 0; n < 4; ++n) {
          int c = cb + n * 16;
          Cs[((size_t)(c >> 6) * NNODES + r) * 64 + (c & 63)] = f2bf(acc[m][n][j]);
        }
    }
}

// ---------- spmm1 + bias + relu, feature-sliced, 4 rows/warp x 2 edge-lanes ----------
// blockIdx&7 = slice (round-robin XCD dispatch -> slice stays in one 4MB L2).
// lane: rloc=l>>4 (row 0..3), el=(l>>3)&1 (edge lane), ft=l&7 (8 bf16 feats = 16B).
__global__ __launch_bounds__(256) void k_spmm1(const int* __restrict__ rs,
                                               const int* __restrict__ scolb,
                                               const float* __restrict__ sval,
                                               const unsigned short* __restrict__ t1s,
                                               const float* __restrict__ b1,
                                               unsigned short* __restrict__ h1) {
  int b = blockIdx.x;
  int slice = b & 7;
  int rgrp = b >> 3;
  int t = threadIdx.x;
  int wid = t >> 6, lane = t & 63;
  int rloc = lane >> 4, el = (lane >> 3) & 1, ft = lane & 7;
  int r = rgrp * 16 + wid * 4 + rloc;
  bool valid = r < NNODES;
  int rr = valid ? r : NNODES - 1;
  const char* tbase = (const char*)(t1s + (size_t)slice * NNODES * 64) + ft * 16;
  int fglob = slice * 64 + ft * 8;
  int e0 = rs[rr];
  int e1 = valid ? rs[rr + 1] : e0;
  f32x2 acc[4] = {};
  int e = e0 + el;
  for (; e + 2 < e1; e += 4) {
    int cA = scolb[e], cB = scolb[e + 2];
    float vA = sval[e], vB = sval[e + 2];
    uint4 a  = *(const uint4*)(tbase + (size_t)(unsigned)cA);
    uint4 bq = *(const uint4*)(tbase + (size_t)(unsigned)cB);
    f32x2 vA2 = {vA, vA}, vB2 = {vB, vB};
    unsigned int ua[4] = {a.x, a.y, a.z, a.w};
    unsigned int ub[4] = {bq.x, bq.y, bq.z, bq.w};
#pragma unroll
    for (int d = 0; d < 4; ++d) {
      f32x2 pa = {asf(ua[d] << 16), asf(ua[d] & 0xffff0000u)};
      f32x2 pb = {asf(ub[d] << 16), asf(ub[d] & 0xffff0000u)};
      acc[d] += vA2 * pa;
      acc[d] += vB2 * pb;
    }
  }
  for (; e < e1; e += 2) {
    int c = scolb[e];
    float v = sval[e];
    uint4 a = *(const uint4*)(tbase + (size_t)(unsigned)c);
    f32x2 v2 = {v, v};
    unsigned int ua[4] = {a.x, a.y, a.z, a.w};
#pragma unroll
    for (int d = 0; d < 4; ++d) {
      f32x2 p = {asf(ua[d] << 16), asf(ua[d] & 0xffff0000u)};
      acc[d] += v2 * p;
    }
  }
  // reduce across the 2 edge-lanes (lane bit 3)
#pragma unroll
  for (int d = 0; d < 4; ++d) {
    acc[d].x += __shfl_xor(acc[d].x, 8);
    acc[d].y += __shfl_xor(acc[d].y, 8);
  }
  if (el == 0 && valid) {
    unsigned int o[4];
#pragma unroll
    for (int d = 0; d < 4; ++d) {
      float s0 = fmaxf(acc[d].x + b1[fglob + 2 * d], 0.f);
      float s1 = fmaxf(acc[d].y + b1[fglob + 2 * d + 1], 0.f);
      o[d] = (unsigned int)f2bf(s0) | ((unsigned int)f2bf(s1) << 16);
    }
    uint4 ov; ov.x = o[0]; ov.y = o[1]; ov.z = o[2]; ov.w = o[3];
    *(uint4*)&h1[(size_t)r * NHID + fglob] = ov;
  }
}

// ---------- GEMM2: t2 = h1 @ W2  (MFMA 16x16x32) ----------
__global__ __launch_bounds__(256) void k_gemm2(const unsigned short* __restrict__ h1,
                                               const float* __restrict__ W2,
                                               float* __restrict__ t2) {
  __shared__ unsigned short w2t[16 * 520];
  int t = threadIdx.x;
#pragma unroll
  for (int i = 0; i < 32; ++i) {
    int p = i * 256 + t;
    int k = p >> 4, f = p & 15;
    w2t[f * 520 + k] = f2bf(W2[p]);
  }
  __syncthreads();
  int w = t >> 6, l = t & 63;
  int l15 = l & 15, l4 = l >> 4;
  int r0 = blockIdx.x * 64 + w * 16;
  int row = r0 + l15; row = row < NNODES ? row : NNODES - 1;
  f32x4 acc = {};
#pragma unroll
  for (int kk = 0; kk < 16; ++kk) {
    short8 af = *(const short8*)&h1[(size_t)row * NHID + kk * 32 + l4 * 8];
    short8 bfr = *(const short8*)&w2t[l15 * 520 + kk * 32 + l4 * 8];
    acc = __builtin_amdgcn_mfma_f32_16x16x32_bf16(af, bfr, acc, 0, 0, 0);
  }
#pragma unroll
  for (int j = 0; j < 4; ++j) {
    int r = r0 + l4 * 4 + j;
    if (r < NNODES) t2[(size_t)r * NCLS + l15] = acc[j];
  }
}

// ---------- spmm2 + bias ----------
__global__ __launch_bounds__(256) void k_spmm2(const int* __restrict__ rs,
                                               const int* __restrict__ scol,
                                               const float* __restrict__ sval,
                                               const float* __restrict__ t2,
                                               const float* __restrict__ b2,
                                               float* __restrict__ out) {
  int t = threadIdx.x;
  int f = t & 15, rl = t >> 4;
  int r = blockIdx.x * 16 + rl;
  if (r >= NNODES) return;
  int e0 = rs[r], e1 = rs[r + 1];
  float a0 = 0.f, a1 = 0.f;
  int e = e0;
  for (; e + 1 < e1; e += 2) {
    a0 += sval[e]     * t2[(size_t)scol[e] * NCLS + f];
    a1 += sval[e + 1] * t2[(size_t)scol[e + 1] * NCLS + f];
  }
  if (e < e1) a0 += sval[e] * t2[(size_t)scol[e] * NCLS + f];
  out[(size_t)r * NCLS + f] = a0 + a1 + b2[f];
}

extern "C" void kernel_launch(void* const* d_in, const int* in_sizes, int n_in,
                              void* d_out, int out_size, void* d_ws, size_t ws_size,
                              hipStream_t stream) {
  (void)in_sizes; (void)n_in; (void)out_size; (void)ws_size;
  const int*   x    = (const int*)  d_in[0];
  const int*   rows = (const int*)  d_in[1];
  const int*   cols = (const int*)  d_in[2];
  const float* vals = (const float*)d_in[3];
  const float* emb  = (const float*)d_in[4];
  const float* W1   = (const float*)d_in[5];
  const float* b1   = (const float*)d_in[6];
  const float* W2   = (const float*)d_in[7];
  const float* b2   = (const float*)d_in[8];
  float* out = (float*)d_out;

  char* ws = (char*)d_ws;
  size_t off = 0;
  auto take = [&](size_t bytes) {
    char* p = ws + off;
    off = (off + bytes + 255) & ~(size_t)255;
    return p;
  };
  unsigned short* h    = (unsigned short*)take((size_t)NNODES * INCH * 2);
  unsigned short* w1t  = (unsigned short*)take((size_t)NHID * INCH * 2);
  unsigned short* t1s  = (unsigned short*)take((size_t)NNODES * NHID * 2);
  unsigned short* h1   = (unsigned short*)take((size_t)NNODES * NHID * 2);
  float*          t2   = (float*)take((size_t)NNODES * NCLS * 4);
  int*            counts = (int*)take((size_t)NNODES * 4);
  int*            cursor = (int*)take((size_t)NNODES * 4);
  int*            rs     = (int*)take((size_t)(NNODES + 1) * 4);
  int*            scol   = (int*)take((size_t)NEDGE * 4);
  int*            scolb  = (int*)take((size_t)NEDGE * 4);
  float*          sval   = (float*)take((size_t)NEDGE * 4);

  hipMemsetAsync(counts, 0, (size_t)NNODES * 4, stream);
  hipMemsetAsync(cursor, 0, (size_t)NNODES * 4, stream);

  k_embed<<<NNODES, 256, 0, stream>>>(x, emb, h);
  k_w1t<<<dim3(INCH / 64, NHID / 64), 256, 0, stream>>>(W1, w1t);
  k_hist<<<(NEDGE + 255) / 256, 256, 0, stream>>>(rows, counts);
  k_scan<<<1, 256, 0, stream>>>(counts, rs);
  k_scatter<<<(NEDGE + 255) / 256, 256, 0, stream>>>(rows, cols, vals, rs, cursor, scol, scolb, sval);
  k_gemm1<<<((NNODES + 127) / 128) * (NHID / 128), 256, 0, stream>>>(h, w1t, t1s);
  k_spmm1<<<((NNODES + 15) / 16) * 8, 256, 0, stream>>>(rs, scolb, sval, t1s, b1, h1);
  k_gemm2<<<(NNODES + 63) / 64, 256, 0, stream>>>(h1, W2, t2);
  k_spmm2<<<(NNODES + 15) / 16, 256, 0, stream>>>(rs, scol, sval, t2, b2, out);
}